// Round 2
// baseline (815.612 us; speedup 1.0000x reference)
//
#include <hip/hip_runtime.h>
#include <math.h>

#define D 384
#define EPS 1e-8f
#define BT 128   // block tile (rows x cols of the dots tile per block)
#define BK 16    // k-chunk staged in LDS

// ---------------- kernel 1: per-row 1/max(||row||, eps) ----------------
__global__ __launch_bounds__(256) void rnorm_kernel(const float* __restrict__ in,
                                                    float* __restrict__ rnorm, int N) {
    int row = blockIdx.x * 4 + (threadIdx.x >> 6);   // one wave per row
    if (row >= N) return;
    int lane = threadIdx.x & 63;
    const float* p = in + (size_t)row * D;
    float s = 0.f;
#pragma unroll
    for (int c = 0; c < D / 64; ++c) {
        float v = p[lane + 64 * c];
        s += v * v;
    }
#pragma unroll
    for (int off = 32; off > 0; off >>= 1) s += __shfl_down(s, off, 64);
    if (lane == 0) rnorm[row] = 1.0f / fmaxf(sqrtf(s), EPS);
}

// ---------------- kernel 2: fused X@X^T tile + per-row argmax ----------------
// Tiled fp32 GEMM structure; never materializes dots. Each block computes a
// 128x128 tile, reduces each row of the tile to (maxdot, argmax), merges into
// global best[] via atomicMax on a packed sortable key.
__global__ __launch_bounds__(256) void maxdot_kernel(const float* __restrict__ in,
                                                     const float* __restrict__ rnorm,
                                                     unsigned long long* __restrict__ best) {
    __shared__ float As[BK][BT];
    __shared__ float Bs[BK][BT];
    __shared__ float rnR[BT], rnC[BT];

    const int t  = threadIdx.x;
    const int tx = t & 15, ty = t >> 4;          // 16x16 thread grid, 8x8 microtile
    const int row0 = blockIdx.y * BT;
    const int col0 = blockIdx.x * BT;

    if (t < 128) rnR[t] = rnorm[row0 + t];
    else if (t < 256) rnC[t - 128] = rnorm[col0 + (t - 128)];

    float acc[8][8] = {};

    for (int kk = 0; kk < D; kk += BK) {
        // stage A (rows row0..row0+127) and B (rows col0..col0+127), k-major in LDS
#pragma unroll
        for (int i = 0; i < 2; ++i) {
            int p  = t + i * 256;         // 0..511 -> 128 rows x 4 float4s
            int r  = p >> 2;
            int kc = (p & 3) << 2;
            const float4 av = *(const float4*)(in + (size_t)(row0 + r) * D + kk + kc);
            As[kc + 0][r] = av.x; As[kc + 1][r] = av.y;
            As[kc + 2][r] = av.z; As[kc + 3][r] = av.w;
            const float4 bv = *(const float4*)(in + (size_t)(col0 + r) * D + kk + kc);
            Bs[kc + 0][r] = bv.x; Bs[kc + 1][r] = bv.y;
            Bs[kc + 2][r] = bv.z; Bs[kc + 3][r] = bv.w;
        }
        __syncthreads();
#pragma unroll
        for (int k = 0; k < BK; ++k) {
            float a[8], b[8];
            *(float4*)&a[0] = *(const float4*)&As[k][ty * 8];
            *(float4*)&a[4] = *(const float4*)&As[k][ty * 8 + 4];
            *(float4*)&b[0] = *(const float4*)&Bs[k][tx * 8];
            *(float4*)&b[4] = *(const float4*)&Bs[k][tx * 8 + 4];
#pragma unroll
            for (int r = 0; r < 8; ++r)
#pragma unroll
                for (int c = 0; c < 8; ++c) acc[r][c] += a[r] * b[c];
        }
        __syncthreads();
    }

    // epilogue: scale by rnorm_i*rnorm_j, mask diagonal, per-row argmax
#pragma unroll
    for (int r = 0; r < 8; ++r) {
        int grow = row0 + ty * 8 + r;
        float rni = rnR[ty * 8 + r];
        unsigned long long key = 0ull;   // < any real key
#pragma unroll
        for (int c = 0; c < 8; ++c) {
            int gcol = col0 + tx * 8 + c;
            float dv = acc[r][c] * rni * rnC[tx * 8 + c];
            unsigned u = __float_as_uint(dv);
            u = (u & 0x80000000u) ? ~u : (u | 0x80000000u);   // sortable-float encode
            unsigned long long k2 = ((unsigned long long)u << 32) | (unsigned)(~gcol);
            if (gcol != grow) key = (key < k2) ? k2 : key;    // ties -> smallest j
        }
        // reduce across the 16 lanes sharing this row group (tx = 0..15)
#pragma unroll
        for (int m = 8; m >= 1; m >>= 1) {
            unsigned long long o = __shfl_xor(key, m, 16);
            key = (key < o) ? o : key;
        }
        if (tx == 0) atomicMax(best + grow, key);
    }
}

// ---------------- kernel 3: exact distance + loss ----------------
__global__ __launch_bounds__(256) void loss_kernel(const float* __restrict__ in,
                                                   const float* __restrict__ rnorm,
                                                   const unsigned long long* __restrict__ best,
                                                   float* __restrict__ out, int N) {
    int row = blockIdx.x * 4 + (threadIdx.x >> 6);   // one wave per row
    if (row >= N) return;
    int lane = threadIdx.x & 63;
    unsigned long long key = best[row];
    int j = (int)(~(unsigned)(key & 0xffffffffull));
    float rni = rnorm[row], rnj = rnorm[j];
    const float* pi = in + (size_t)row * D;
    const float* pj = in + (size_t)j * D;
    float s = 0.f;
#pragma unroll
    for (int c = 0; c < D / 64; ++c) {
        float xi = pi[lane + 64 * c] * rni;
        float xj = pj[lane + 64 * c] * rnj;
        float dvv = xi - xj + EPS;                   // ||x - nn_x + eps||
        s += dvv * dvv;
    }
#pragma unroll
    for (int off = 32; off > 0; off >>= 1) s += __shfl_down(s, off, 64);
    if (lane == 0) {
        float dist = sqrtf(s);
        atomicAdd(out, -logf(dist + EPS) / (float)N);
    }
}

extern "C" void kernel_launch(void* const* d_in, const int* in_sizes, int n_in,
                              void* d_out, int out_size, void* d_ws, size_t ws_size,
                              hipStream_t stream) {
    const float* in = (const float*)d_in[0];
    float* out = (float*)d_out;
    const int N = in_sizes[0] / D;                   // 8192

    float* rnorm = (float*)d_ws;
    unsigned long long* best =
        (unsigned long long*)((char*)d_ws + (((size_t)N * 4 + 255) & ~(size_t)255));

    (void)hipMemsetAsync(best, 0, (size_t)N * 8, stream);  // ws is poisoned 0xAA each call
    (void)hipMemsetAsync(out, 0, sizeof(float), stream);

    rnorm_kernel<<<N / 4, 256, 0, stream>>>(in, rnorm, N);
    dim3 g(N / BT, N / BT);
    maxdot_kernel<<<g, 256, 0, stream>>>(in, rnorm, best);
    loss_kernel<<<N / 4, 256, 0, stream>>>(in, rnorm, best, out, N);
}

// Round 3
// 296.849 us; speedup vs baseline: 2.7476x; 2.7476x over previous
//
#include <hip/hip_runtime.h>
#include <hip/hip_bf16.h>
#include <math.h>

#define D 384
#define EPS 1e-8f
#define BM 128
#define BN 128
#define BK 32          // k-chunk per LDS tile == MFMA K

typedef __bf16  bf16x8  __attribute__((ext_vector_type(8)));
typedef float   floatx4 __attribute__((ext_vector_type(4)));

// ---------------- kernel 1: rnorm + normalized bf16 cast ----------------
__global__ __launch_bounds__(256) void prep_kernel(const float* __restrict__ in,
                                                   float* __restrict__ rnorm,
                                                   __hip_bfloat16* __restrict__ xb, int N) {
    int row = blockIdx.x * 4 + (threadIdx.x >> 6);   // one wave per row
    if (row >= N) return;
    int lane = threadIdx.x & 63;
    const float* p = in + (size_t)row * D;
    float v[6];
    float s = 0.f;
#pragma unroll
    for (int c = 0; c < 6; ++c) { v[c] = p[lane + 64 * c]; s += v[c] * v[c]; }
#pragma unroll
    for (int off = 32; off >= 1; off >>= 1) s += __shfl_xor(s, off, 64);  // all lanes get total
    float rn = 1.0f / fmaxf(sqrtf(s), EPS);
    if (lane == 0) rnorm[row] = rn;
    __hip_bfloat16* q = xb + (size_t)row * D;
#pragma unroll
    for (int c = 0; c < 6; ++c) q[lane + 64 * c] = __float2bfloat16(v[c] * rn);
}

// ---------------- kernel 2: bf16 MFMA X@X^T + fused per-row argmax ----------------
// m97-style gemm_bt: LDS tiles [row][BK] bf16, 64 B/row, staged with
// global_load_lds width=16 (lane order == LDS-contiguous order).
__global__ __launch_bounds__(256) void maxdot_mfma(const __hip_bfloat16* __restrict__ xb,
                                                   unsigned long long* __restrict__ best) {
    __shared__ __hip_bfloat16 As[BM * BK];   // row-major, 64 B per row
    __shared__ __hip_bfloat16 Bs[BN * BK];

    const int t    = threadIdx.x;
    const int lane = t & 63;
    const int wave = t >> 6;              // 4 waves: 2x2, each computes 64x64
    const int wm   = wave >> 1, wn = wave & 1;
    const int quad = lane >> 4, l16 = lane & 15;
    const int row0 = blockIdx.y * BM;
    const int col0 = blockIdx.x * BN;

    floatx4 acc[4][4];
#pragma unroll
    for (int i = 0; i < 4; ++i)
#pragma unroll
        for (int j = 0; j < 4; ++j) acc[i][j] = (floatx4){0.f, 0.f, 0.f, 0.f};

    const int r_st = t >> 2;              // staging: q = pass*256+t -> row q>>2
    const int o16  = (t & 3) * 16;        // byte offset within 64-B row

    for (int kk = 0; kk < D; kk += BK) {
#pragma unroll
        for (int pass = 0; pass < 2; ++pass) {
            int r = r_st + pass * 64;
            const char* ga = (const char*)(xb + (size_t)(row0 + r) * D + kk) + o16;
            const char* gb = (const char*)(xb + (size_t)(col0 + r) * D + kk) + o16;
            char* la = (char*)As + r * 64 + o16;
            char* lb = (char*)Bs + r * 64 + o16;
            __builtin_amdgcn_global_load_lds((const __attribute__((address_space(1))) void*)ga,
                                             (__attribute__((address_space(3))) void*)la, 16, 0, 0);
            __builtin_amdgcn_global_load_lds((const __attribute__((address_space(1))) void*)gb,
                                             (__attribute__((address_space(3))) void*)lb, 16, 0, 0);
        }
        __syncthreads();   // drains vmcnt before LDS reads

        // fragments: A[m=l16][k=quad*8+j]  (16 B = 8 bf16 contiguous along k)
        bf16x8 af[4], bfr[4];
#pragma unroll
        for (int mi = 0; mi < 4; ++mi)
            af[mi] = *(const bf16x8*)((const char*)As + (wm * 64 + mi * 16 + l16) * 64 + quad * 16);
#pragma unroll
        for (int ni = 0; ni < 4; ++ni)
            bfr[ni] = *(const bf16x8*)((const char*)Bs + (wn * 64 + ni * 16 + l16) * 64 + quad * 16);
#pragma unroll
        for (int mi = 0; mi < 4; ++mi)
#pragma unroll
            for (int ni = 0; ni < 4; ++ni)
                acc[mi][ni] = __builtin_amdgcn_mfma_f32_16x16x32_bf16(af[mi], bfr[ni], acc[mi][ni], 0, 0, 0);
        __syncthreads();   // before next tile overwrites LDS
    }

    // epilogue: C/D layout col = l16, row = quad*4 + reg. Per-row argmax.
#pragma unroll
    for (int mi = 0; mi < 4; ++mi) {
#pragma unroll
        for (int reg = 0; reg < 4; ++reg) {
            int grow = row0 + wm * 64 + mi * 16 + quad * 4 + reg;
            unsigned long long key = 0ull;   // below any real key
#pragma unroll
            for (int ni = 0; ni < 4; ++ni) {
                int gcol = col0 + wn * 64 + ni * 16 + l16;
                float dv = acc[mi][ni][reg];
                unsigned u = __float_as_uint(dv);
                u = (u & 0x80000000u) ? ~u : (u | 0x80000000u);   // sortable-float
                unsigned long long k2 = ((unsigned long long)u << 32) | (unsigned)(~gcol);
                if (gcol != grow) key = (key < k2) ? k2 : key;    // ties -> smallest j
            }
            // reduce across the 16 lanes of this quad (xor masks stay in-quad)
#pragma unroll
            for (int m = 8; m >= 1; m >>= 1) {
                unsigned long long o = __shfl_xor(key, m, 64);
                key = (key < o) ? o : key;
            }
            if (l16 == 0) atomicMax(best + grow, key);
        }
    }
}

// ---------------- kernel 3: exact fp32 distance + loss ----------------
__global__ __launch_bounds__(256) void loss_kernel(const float* __restrict__ in,
                                                   const float* __restrict__ rnorm,
                                                   const unsigned long long* __restrict__ best,
                                                   float* __restrict__ out, int N) {
    int row = blockIdx.x * 4 + (threadIdx.x >> 6);   // one wave per row
    if (row >= N) return;
    int lane = threadIdx.x & 63;
    unsigned long long key = best[row];
    int j = (int)(~(unsigned)(key & 0xffffffffull));
    float rni = rnorm[row], rnj = rnorm[j];
    const float* pi = in + (size_t)row * D;
    const float* pj = in + (size_t)j * D;
    float s = 0.f;
#pragma unroll
    for (int c = 0; c < 6; ++c) {
        float xi = pi[lane + 64 * c] * rni;
        float xj = pj[lane + 64 * c] * rnj;
        float dvv = xi - xj + EPS;                   // ||x - nn_x + eps||
        s += dvv * dvv;
    }
#pragma unroll
    for (int off = 32; off > 0; off >>= 1) s += __shfl_down(s, off, 64);
    if (lane == 0) {
        float dist = sqrtf(s);
        atomicAdd(out, -logf(dist + EPS) / (float)N);
    }
}

extern "C" void kernel_launch(void* const* d_in, const int* in_sizes, int n_in,
                              void* d_out, int out_size, void* d_ws, size_t ws_size,
                              hipStream_t stream) {
    const float* in = (const float*)d_in[0];
    float* out = (float*)d_out;
    const int N = in_sizes[0] / D;                   // 8192

    // workspace layout: rnorm (N f32) | best (N u64) | xb (N*D bf16)
    char* ws = (char*)d_ws;
    float* rnorm = (float*)ws;
    unsigned long long* best = (unsigned long long*)(ws + 64 * 1024);
    __hip_bfloat16* xb = (__hip_bfloat16*)(ws + 192 * 1024);

    (void)hipMemsetAsync(best, 0, (size_t)N * 8, stream);  // ws re-poisoned each call
    (void)hipMemsetAsync(out, 0, sizeof(float), stream);

    prep_kernel<<<N / 4, 256, 0, stream>>>(in, rnorm, xb, N);
    dim3 g(N / BN, N / BM);
    maxdot_mfma<<<g, 256, 0, stream>>>(xb, best);
    loss_kernel<<<N / 4, 256, 0, stream>>>(in, rnorm, best, out, N);
}

// Round 4
// 180.815 us; speedup vs baseline: 4.5108x; 1.6417x over previous
//
#include <hip/hip_runtime.h>
#include <hip/hip_bf16.h>
#include <math.h>

#define D 384
#define EPS 1e-8f
#define BM 128
#define BN 128
#define BK 64          // k-chunk per LDS tile (2 MFMA K-steps)

typedef __bf16  bf16x8  __attribute__((ext_vector_type(8)));
typedef float   floatx4 __attribute__((ext_vector_type(4)));

__device__ __forceinline__ unsigned long long pack_key(float dv, int idx) {
    unsigned u = __float_as_uint(dv);
    u = (u & 0x80000000u) ? ~u : (u | 0x80000000u);        // sortable-float encode
    return ((unsigned long long)u << 32) | (unsigned)(~idx); // ties -> smallest idx
}

// ---------------- kernel 1: rnorm + normalized bf16 cast ----------------
__global__ __launch_bounds__(256) void prep_kernel(const float* __restrict__ in,
                                                   float* __restrict__ rnorm,
                                                   __hip_bfloat16* __restrict__ xb, int N) {
    int row = blockIdx.x * 4 + (threadIdx.x >> 6);   // one wave per row
    if (row >= N) return;
    int lane = threadIdx.x & 63;
    const float* p = in + (size_t)row * D;
    float v[6];
    float s = 0.f;
#pragma unroll
    for (int c = 0; c < 6; ++c) { v[c] = p[lane + 64 * c]; s += v[c] * v[c]; }
#pragma unroll
    for (int off = 32; off >= 1; off >>= 1) s += __shfl_xor(s, off, 64);
    float rn = 1.0f / fmaxf(sqrtf(s), EPS);
    if (lane == 0) rnorm[row] = rn;
    __hip_bfloat16* q = xb + (size_t)row * D;
#pragma unroll
    for (int c = 0; c < 6; ++c) q[lane + 64 * c] = __float2bfloat16(v[c] * rn);
}

// ---------------- kernel 2: bf16 MFMA, lower-triangle blocks only ----------------
// Block (bx,by), bx<=by: computes tile dots[row0+.., col0+..], updates
// best[] for BOTH its rows (argmax over cols) and its cols (argmax over rows).
__global__ __launch_bounds__(256) void maxdot_mfma(const __hip_bfloat16* __restrict__ xb,
                                                   unsigned long long* __restrict__ best) {
    __shared__ __hip_bfloat16 As[BM * BK];   // row-major, 128 B per row, 16 KB
    __shared__ __hip_bfloat16 Bs[BN * BK];

    const int t    = threadIdx.x;
    const int lane = t & 63;
    const int wave = t >> 6;              // 4 waves: 2x2, each computes 64x64
    const int wm   = wave >> 1, wn = wave & 1;
    const int quad = lane >> 4, l16 = lane & 15;

    // linear block id -> lower-triangle (bx, by), bx <= by
    int l  = blockIdx.x;
    int by = (int)((sqrtf(8.f * (float)l + 1.f) - 1.f) * 0.5f);
    while ((by + 1) * (by + 2) / 2 <= l) ++by;
    while (by * (by + 1) / 2 > l) --by;
    int bx = l - by * (by + 1) / 2;
    const int row0 = by * BM;
    const int col0 = bx * BN;

    floatx4 acc[4][4];
#pragma unroll
    for (int i = 0; i < 4; ++i)
#pragma unroll
        for (int j = 0; j < 4; ++j) acc[i][j] = (floatx4){0.f, 0.f, 0.f, 0.f};

    for (int kk = 0; kk < D; kk += BK) {
#pragma unroll
        for (int pass = 0; pass < 4; ++pass) {     // 128 rows x 128 B per matrix
            int p = pass * 256 + t;
            int r = p >> 3;
            int ob = (p & 7) * 16;                 // byte offset in 128-B row
            const char* ga = (const char*)(xb + (size_t)(row0 + r) * D + kk) + ob;
            const char* gb = (const char*)(xb + (size_t)(col0 + r) * D + kk) + ob;
            __builtin_amdgcn_global_load_lds((const __attribute__((address_space(1))) void*)ga,
                                             (__attribute__((address_space(3))) void*)((char*)As + p * 16), 16, 0, 0);
            __builtin_amdgcn_global_load_lds((const __attribute__((address_space(1))) void*)gb,
                                             (__attribute__((address_space(3))) void*)((char*)Bs + p * 16), 16, 0, 0);
        }
        __syncthreads();

#pragma unroll
        for (int kc = 0; kc < 2; ++kc) {           // two 32-k MFMA steps per tile
            bf16x8 af[4], bfr[4];
#pragma unroll
            for (int mi = 0; mi < 4; ++mi)
                af[mi] = *(const bf16x8*)((const char*)As + (wm * 64 + mi * 16 + l16) * 128 + kc * 64 + quad * 16);
#pragma unroll
            for (int ni = 0; ni < 4; ++ni)
                bfr[ni] = *(const bf16x8*)((const char*)Bs + (wn * 64 + ni * 16 + l16) * 128 + kc * 64 + quad * 16);
#pragma unroll
            for (int mi = 0; mi < 4; ++mi)
#pragma unroll
                for (int ni = 0; ni < 4; ++ni)
                    acc[mi][ni] = __builtin_amdgcn_mfma_f32_16x16x32_bf16(af[mi], bfr[ni], acc[mi][ni], 0, 0, 0);
        }
        __syncthreads();
    }

    // ---- row-side argmax: C/D layout col=l16, row=quad*4+reg ----
#pragma unroll
    for (int mi = 0; mi < 4; ++mi) {
#pragma unroll
        for (int reg = 0; reg < 4; ++reg) {
            int grow = row0 + wm * 64 + mi * 16 + quad * 4 + reg;
            unsigned long long key = 0ull;
#pragma unroll
            for (int ni = 0; ni < 4; ++ni) {
                int gcol = col0 + wn * 64 + ni * 16 + l16;
                unsigned long long k2 = pack_key(acc[mi][ni][reg], gcol);
                if (gcol != grow) key = (key < k2) ? k2 : key;   // masks diag (bx==by only)
            }
#pragma unroll
            for (int m = 8; m >= 1; m >>= 1) {   // reduce over l16 within quad
                unsigned long long o = __shfl_xor(key, m, 64);
                key = (key < o) ? o : key;
            }
            if (l16 == 0) atomicMax(best + grow, key);
        }
    }

    // ---- col-side argmax (transpose contribution), off-diagonal blocks only ----
    if (bx != by) {
#pragma unroll
        for (int ni = 0; ni < 4; ++ni) {
            int gcol = col0 + wn * 64 + ni * 16 + l16;
            unsigned long long key = 0ull;
#pragma unroll
            for (int mi = 0; mi < 4; ++mi)
#pragma unroll
                for (int reg = 0; reg < 4; ++reg) {
                    int grow = row0 + wm * 64 + mi * 16 + quad * 4 + reg;
                    unsigned long long k2 = pack_key(acc[mi][ni][reg], grow);
                    key = (key < k2) ? k2 : key;                 // grow != gcol always
                }
#pragma unroll
            for (int m = 16; m <= 32; m <<= 1) { // reduce over quad (same l16)
                unsigned long long o = __shfl_xor(key, m, 64);
                key = (key < o) ? o : key;
            }
            if (quad == 0) atomicMax(best + gcol, key);
        }
    }
}

// ---------------- kernel 3: exact fp32 distance + loss (few atomics) ----------------
__global__ __launch_bounds__(256) void loss_kernel(const float* __restrict__ in,
                                                   const float* __restrict__ rnorm,
                                                   const unsigned long long* __restrict__ best,
                                                   float* __restrict__ out, int N) {
    __shared__ float part[4];
    const int wave = threadIdx.x >> 6, lane = threadIdx.x & 63;
    const int gw = blockIdx.x * 4 + wave;            // 256 waves total
    float local = 0.f;
    for (int row = gw; row < N; row += 256) {
        unsigned long long key = best[row];
        int j = (int)(~(unsigned)(key & 0xffffffffull));
        float rni = rnorm[row], rnj = rnorm[j];
        const float* pi = in + (size_t)row * D;
        const float* pj = in + (size_t)j * D;
        float s = 0.f;
#pragma unroll
        for (int c = 0; c < 6; ++c) {
            float xi = pi[lane + 64 * c] * rni;
            float xj = pj[lane + 64 * c] * rnj;
            float dvv = xi - xj + EPS;               // ||x - nn_x + eps||
            s += dvv * dvv;
        }
#pragma unroll
        for (int off = 32; off > 0; off >>= 1) s += __shfl_down(s, off, 64);
        if (lane == 0) local += -logf(sqrtf(s) + EPS);
    }
    if (lane == 0) part[wave] = local;
    __syncthreads();
    if (threadIdx.x == 0)
        atomicAdd(out, (part[0] + part[1] + part[2] + part[3]) / (float)N);
}

extern "C" void kernel_launch(void* const* d_in, const int* in_sizes, int n_in,
                              void* d_out, int out_size, void* d_ws, size_t ws_size,
                              hipStream_t stream) {
    const float* in = (const float*)d_in[0];
    float* out = (float*)d_out;
    const int N = in_sizes[0] / D;                   // 8192

    // workspace layout: rnorm (N f32) | best (N u64) | xb (N*D bf16)
    char* ws = (char*)d_ws;
    float* rnorm = (float*)ws;
    unsigned long long* best = (unsigned long long*)(ws + 64 * 1024);
    __hip_bfloat16* xb = (__hip_bfloat16*)(ws + 192 * 1024);

    (void)hipMemsetAsync(best, 0, (size_t)N * 8, stream);  // ws re-poisoned each call
    (void)hipMemsetAsync(out, 0, sizeof(float), stream);

    prep_kernel<<<N / 4, 256, 0, stream>>>(in, rnorm, xb, N);
    int nb = N / BM;                                 // 64
    maxdot_mfma<<<nb * (nb + 1) / 2, 256, 0, stream>>>(xb, best);
    loss_kernel<<<64, 256, 0, stream>>>(in, rnorm, best, out, N);
}